// Round 7
// baseline (346.215 us; speedup 1.0000x reference)
//
#include <hip/hip_runtime.h>
#include <math.h>

namespace {

constexpr int B_ = 256;
constexpr int R_ = 1152;
constexpr int C_ = 10;
constexpr int O_ = 16;
constexpr int I_ = 8;
constexpr int CO_ = C_ * O_;          // 160
constexpr int WRI_ = C_ * O_ * I_;    // 1280 floats of W per route

constexpr int KS_  = 32;              // r-splits in s-phase
constexpr int RC_  = R_ / KS_;        // 36 routes per s-block
constexpr int RT_  = 2;               // routes per a-block -> 576 blocks
constexpr int NA_  = R_ / RT_;        // 576 a-blocks

// fallback tier-3 params
constexpr int KSF_ = 16;
constexpr int RCF_ = R_ / KSF_;       // 72
constexpr int MBF_ = 16;

// ws layout (float offsets) — sA|sB|bij contiguous so k_tr zeroes one range
constexpr size_t XT_OFF    = 0;                          // [R][B][I]
constexpr size_t XT_N      = (size_t)R_ * B_ * I_;       // 2,359,296
constexpr size_t SA_OFF    = XT_OFF + XT_N;              // [CO][B] raw s, iter 0/2
constexpr size_t SAB_N     = (size_t)CO_ * B_;           // 40,960
constexpr size_t SB_OFF    = SA_OFF + SAB_N;             // [CO][B] raw s, iter 1
constexpr size_t BIJ_OFF   = SB_OFF + SAB_N;             // [C][R]
constexpr size_t BIJ_N     = (size_t)C_ * R_;            // 11,520
constexpr size_t ZERO_N    = 2 * SAB_N + BIJ_N;          // 93,440 floats
constexpr size_t BIJD_OFF  = BIJ_OFF + BIJ_N;            // diag dummy, 2 copies
constexpr size_t FL_TOTAL  = BIJD_OFF + 2 * BIJ_N;

__device__ __forceinline__ float squashf(float s) {
    // faithful to reference: s^2*s/((1+s^2)*sqrt(s^2)) == s*|s|/(1+s^2)
    return s * fabsf(s) / (1.0f + s * s);
}

// ===========================================================================
// k_tr: x[b,r,i] -> xT[r,b,i]; zero sA|sB|bij.  tile 8 b x 32 r.  grid 1152.
// ===========================================================================
__global__ __launch_bounds__(256) void k_tr(const float* __restrict__ x,
                                            float* __restrict__ xT,
                                            float* __restrict__ zbase) {
    __shared__ float t[8][32][8];
    const int tid = threadIdx.x;
    {
        const int gi = blockIdx.x * 256 + tid;
        if (gi < (int)(ZERO_N / 4))
            ((float4*)zbase)[gi] = make_float4(0.f, 0.f, 0.f, 0.f);
    }
    const int r0 = (blockIdx.x % 36) * 32;
    const int b0 = (blockIdx.x / 36) * 8;
    {
        const int rl = tid & 31, bl = tid >> 5;
        const float4* p = (const float4*)(x + ((size_t)(b0 + bl) * R_ + (r0 + rl)) * I_);
        const float4 a0 = p[0], a1 = p[1];
        float* d = &t[bl][rl][0];
        *(float4*)d = a0;
        *(float4*)(d + 4) = a1;
    }
    __syncthreads();
    {
        const int f = tid & 7, rw = tid >> 3;   // f = b-local
        const float* s8 = &t[f][rw][0];
        const float4 a0 = *(const float4*)s8, a1 = *(const float4*)(s8 + 4);
        float* d = xT + ((size_t)(r0 + rw) * B_ + (b0 + f)) * I_;
        *(float4*)d = a0;
        *(float4*)(d + 4) = a1;
    }
}

// ===========================================================================
// k_s8: s_dst[co][b] (+=, atomic) sum_{r in chunk} cw[r,c]*dot(W[r,c,o,:],xT[r,b,:])
// grid 640: bid = c*64 + ks*2 + bh.  c-stride 64 == 0 (mod 8): all 10
// c-copies of an x-chunk land on one XCD (L2 reuse).
// NB=2: each thread covers 2 b's (acc[4][2]) -> the 8 W ds_read_b128 per r
// amortize over 128 fma: LDS:VALU cycles 96:256 (was 96:64 at NB=1 -> was
// LDS-issue-bound).  W chunk (36 r x 128) LDS-staged with softmax weight
// folded in; per-block softmax preamble from bijT.
// ===========================================================================
template <bool UNIFORM>
__global__ __launch_bounds__(256) void k_s8(const float* __restrict__ xT,
                                            const float* __restrict__ Wm,
                                            const float* __restrict__ bijT,
                                            float* __restrict__ s_dst) {
    __shared__ __align__(16) float wl[RC_ * 128];   // 18.4 KB
    __shared__ float cwch[RC_];
    __shared__ float sred[8];

    const int tid   = threadIdx.x;
    const int lane  = tid & 63;
    const int bid   = blockIdx.x;
    const int c     = bid >> 6;           // 0..9
    const int chunk = bid & 63;
    const int ks    = chunk >> 1;         // 0..31
    const int bh    = chunk & 1;          // 0..1
    const int r0    = ks * RC_;

    // ---- per-block softmax over routes for capsule c -> cwch[0..35] ----
    if (!UNIFORM) {
        const float* bc = bijT + (size_t)c * R_;
        float bv[5];
        float m = -1e30f;
        #pragma unroll
        for (int k = 0; k < 5; ++k) {
            const int r = tid + 256 * k;
            bv[k] = (r < R_) ? bc[r] : -1e30f;
            m = fmaxf(m, bv[k]);
        }
        #pragma unroll
        for (int off = 32; off > 0; off >>= 1)
            m = fmaxf(m, __shfl_down(m, off, 64));
        if (lane == 0) sred[tid >> 6] = m;
        __syncthreads();
        const float bm = fmaxf(fmaxf(sred[0], sred[1]), fmaxf(sred[2], sred[3]));
        float se = 0.f;
        #pragma unroll
        for (int k = 0; k < 5; ++k)
            se += (bv[k] > -1e29f) ? expf(bv[k] - bm) : 0.f;
        #pragma unroll
        for (int off = 32; off > 0; off >>= 1)
            se += __shfl_down(se, off, 64);
        if (lane == 0) sred[4 + (tid >> 6)] = se;
        __syncthreads();
        const float inv = 1.0f / (sred[4] + sred[5] + sred[6] + sred[7]);
        if (tid < RC_) cwch[tid] = expf(bc[r0 + tid] - bm) * inv;
        __syncthreads();
    }

    // ---- stage cw-scaled W chunk: 36 r x 32 f4 = 1152 f4 ----
    {
        const float4* src = (const float4*)(Wm + ((size_t)r0 * C_ + c) * 128);
        float4* dst = (float4*)wl;
        #pragma unroll
        for (int k = 0; k < (RC_ * 32 + 255) / 256; ++k) {
            const int idx = tid + 256 * k;
            if (idx < RC_ * 32) {
                const int r = idx >> 5, q = idx & 31;
                float4 wv = src[(size_t)r * (C_ * 32) + q];
                const float cw = UNIFORM ? (1.0f / (float)R_) : cwch[r];
                wv.x *= cw; wv.y *= cw; wv.z *= cw; wv.w *= cw;
                dst[idx] = wv;
            }
        }
    }
    __syncthreads();

    const int o0 = (tid >> 6) * 4;        // wave-uniform -> LDS broadcast reads
    // b = bh*128 + bb*64 + lane, bb in {0,1}
    const float* xbase = xT + ((size_t)r0 * B_ + bh * 128 + lane) * I_;

    float acc[4][2];
    #pragma unroll
    for (int oo = 0; oo < 4; ++oo) { acc[oo][0] = 0.f; acc[oo][1] = 0.f; }

    #pragma unroll 2
    for (int r = 0; r < RC_; ++r) {
        const float* xr = xbase + (size_t)r * B_ * I_;
        const float4 a00 = ((const float4*)xr)[0];
        const float4 a01 = ((const float4*)xr)[1];
        const float4 a10 = ((const float4*)(xr + 64 * I_))[0];
        const float4 a11 = ((const float4*)(xr + 64 * I_))[1];
        const float4* wp = (const float4*)&wl[r * 128 + o0 * 8];
        #pragma unroll
        for (int oo = 0; oo < 4; ++oo) {
            const float4 w0 = wp[oo * 2 + 0];
            const float4 w1 = wp[oo * 2 + 1];
            float a = acc[oo][0];
            a = fmaf(a00.x, w0.x, a);
            a = fmaf(a00.y, w0.y, a);
            a = fmaf(a00.z, w0.z, a);
            a = fmaf(a00.w, w0.w, a);
            a = fmaf(a01.x, w1.x, a);
            a = fmaf(a01.y, w1.y, a);
            a = fmaf(a01.z, w1.z, a);
            a = fmaf(a01.w, w1.w, a);
            acc[oo][0] = a;
            float b = acc[oo][1];
            b = fmaf(a10.x, w0.x, b);
            b = fmaf(a10.y, w0.y, b);
            b = fmaf(a10.z, w0.z, b);
            b = fmaf(a10.w, w0.w, b);
            b = fmaf(a11.x, w1.x, b);
            b = fmaf(a11.y, w1.y, b);
            b = fmaf(a11.z, w1.z, b);
            b = fmaf(a11.w, w1.w, b);
            acc[oo][1] = b;
        }
    }

    // s layout [co][b]: lanes (b) coalesce -> 8 coalesced wave-atomics
    float* sp = s_dst + (size_t)(c * O_ + o0) * B_ + bh * 128 + lane;
    #pragma unroll
    for (int oo = 0; oo < 4; ++oo) {
        atomicAdd(sp + (size_t)oo * B_, acc[oo][0]);
        atomicAdd(sp + (size_t)oo * B_ + 64, acc[oo][1]);
    }
}

// ===========================================================================
// a7_body: bij_dst[c, r0+rr] += (1/B) sum_o sum_i W[r,c,o,i]*M[rr,co,i],
//          M[rr,co,i] = sum_b squash(s_read[co][b]) * xT[r,b,i]
// 320 thr = 80 co-pairs x 4 b-groups of 64.  Each x LDS broadcast feeds
// 2 co -> LDS:VALU cycles 48:64 per b (was 48:32 at 1 co -> LDS-bound).
// Blocks 0..39 zero s_zero (buffer the NEXT s-launch accumulates into).
// ===========================================================================
struct A7Sh {
    float xrow[RT_ * B_ * I_];   // 16 KB
    float part[RT_][320];        // 2.5 KB
};

__device__ __forceinline__ void a7_body(int bid, A7Sh& sh,
                                        const float* __restrict__ xT,
                                        const float* __restrict__ Wm,
                                        const float* __restrict__ s_read,
                                        float* __restrict__ s_zero,
                                        float* __restrict__ bij_dst) {
    const int tid = threadIdx.x;
    const int r0  = bid * RT_;

    if (s_zero != nullptr && bid < 40 && tid < 256) {
        ((float4*)s_zero)[bid * 256 + tid] = make_float4(0.f, 0.f, 0.f, 0.f);
    }

    for (int k = tid; k < RT_ * B_ * I_ / 4; k += 320)
        ((float4*)sh.xrow)[k] = ((const float4*)(xT + (size_t)r0 * B_ * I_))[k];
    __syncthreads();

    const int cp = tid % 80;          // co pair: co = 2cp, 2cp+1 (same capsule)
    const int bg = tid / 80;          // 0..3
    const int b0 = bg * 64;

    float acc[RT_][2][8];
    #pragma unroll
    for (int rr = 0; rr < RT_; ++rr)
        #pragma unroll
        for (int j = 0; j < 2; ++j)
            #pragma unroll
            for (int i = 0; i < 8; ++i) acc[rr][j][i] = 0.f;

    const float* vA = s_read + (size_t)(2 * cp) * B_ + b0;   // [co][b]
    const float* vB = vA + B_;

    #pragma unroll 2
    for (int bb = 0; bb < 64; bb += 4) {
        const float4 a4 = *(const float4*)(vA + bb);
        const float4 b4 = *(const float4*)(vB + bb);
        float va[4], vb[4];
        va[0] = squashf(a4.x); va[1] = squashf(a4.y);
        va[2] = squashf(a4.z); va[3] = squashf(a4.w);
        vb[0] = squashf(b4.x); vb[1] = squashf(b4.y);
        vb[2] = squashf(b4.z); vb[3] = squashf(b4.w);
        #pragma unroll
        for (int j = 0; j < 4; ++j) {
            const int b = b0 + bb + j;
            #pragma unroll
            for (int rr = 0; rr < RT_; ++rr) {
                const float4 y0 = *(const float4*)(&sh.xrow[(rr * B_ + b) * I_]);
                const float4 y1 = *(const float4*)(&sh.xrow[(rr * B_ + b) * I_ + 4]);
                acc[rr][0][0] = fmaf(va[j], y0.x, acc[rr][0][0]);
                acc[rr][0][1] = fmaf(va[j], y0.y, acc[rr][0][1]);
                acc[rr][0][2] = fmaf(va[j], y0.z, acc[rr][0][2]);
                acc[rr][0][3] = fmaf(va[j], y0.w, acc[rr][0][3]);
                acc[rr][0][4] = fmaf(va[j], y1.x, acc[rr][0][4]);
                acc[rr][0][5] = fmaf(va[j], y1.y, acc[rr][0][5]);
                acc[rr][0][6] = fmaf(va[j], y1.z, acc[rr][0][6]);
                acc[rr][0][7] = fmaf(va[j], y1.w, acc[rr][0][7]);
                acc[rr][1][0] = fmaf(vb[j], y0.x, acc[rr][1][0]);
                acc[rr][1][1] = fmaf(vb[j], y0.y, acc[rr][1][1]);
                acc[rr][1][2] = fmaf(vb[j], y0.z, acc[rr][1][2]);
                acc[rr][1][3] = fmaf(vb[j], y0.w, acc[rr][1][3]);
                acc[rr][1][4] = fmaf(vb[j], y1.x, acc[rr][1][4]);
                acc[rr][1][5] = fmaf(vb[j], y1.y, acc[rr][1][5]);
                acc[rr][1][6] = fmaf(vb[j], y1.z, acc[rr][1][6]);
                acc[rr][1][7] = fmaf(vb[j], y1.w, acc[rr][1][7]);
            }
        }
    }

    #pragma unroll
    for (int rr = 0; rr < RT_; ++rr) {
        const float* wp = Wm + (((size_t)(r0 + rr)) * CO_ + 2 * cp) * I_;
        const float4 wa0 = *(const float4*)wp;
        const float4 wa1 = *(const float4*)(wp + 4);
        const float4 wb0 = *(const float4*)(wp + 8);
        const float4 wb1 = *(const float4*)(wp + 12);
        float p0 = acc[rr][0][0] * wa0.x;
        p0 = fmaf(acc[rr][0][1], wa0.y, p0);
        p0 = fmaf(acc[rr][0][2], wa0.z, p0);
        p0 = fmaf(acc[rr][0][3], wa0.w, p0);
        p0 = fmaf(acc[rr][0][4], wa1.x, p0);
        p0 = fmaf(acc[rr][0][5], wa1.y, p0);
        p0 = fmaf(acc[rr][0][6], wa1.z, p0);
        p0 = fmaf(acc[rr][0][7], wa1.w, p0);
        float p1 = acc[rr][1][0] * wb0.x;
        p1 = fmaf(acc[rr][1][1], wb0.y, p1);
        p1 = fmaf(acc[rr][1][2], wb0.z, p1);
        p1 = fmaf(acc[rr][1][3], wb0.w, p1);
        p1 = fmaf(acc[rr][1][4], wb1.x, p1);
        p1 = fmaf(acc[rr][1][5], wb1.y, p1);
        p1 = fmaf(acc[rr][1][6], wb1.z, p1);
        p1 = fmaf(acc[rr][1][7], wb1.w, p1);
        sh.part[rr][tid] = p0 + p1;
    }
    __syncthreads();

    // part[rr][bg*80 + c*8 + q], q in [0,8): reduce 32 values per (rr,c)
    if (tid < RT_ * C_) {
        const int r = tid / C_, c2 = tid % C_;
        float s = 0.f;
        #pragma unroll
        for (int g2 = 0; g2 < 4; ++g2)
            #pragma unroll
            for (int q = 0; q < 8; ++q)
                s += sh.part[r][g2 * 80 + c2 * 8 + q];
        bij_dst[(size_t)c2 * R_ + (r0 + r)] += s * (1.0f / (float)B_);
    }
}

__global__ __launch_bounds__(320) void k_a7(const float* __restrict__ xT,
                                            const float* __restrict__ Wm,
                                            const float* __restrict__ s_read,
                                            float* __restrict__ s_zero,
                                            float* __restrict__ bijT) {
    __shared__ A7Sh sh;
    a7_body(blockIdx.x, sh, xT, Wm, s_read, s_zero, bijT);
}

// Diagnostic: loops the a7 body 4x into a dummy bij so the dispatch exceeds
// the 44 us ws-poison fills and surfaces in rocprof top-5 WITH counters.
// Per-body cost ~= dur/4.  Runs after the real pipeline; outputs unused.
__global__ __launch_bounds__(320) void k_a7diag(const float* __restrict__ xT,
                                                const float* __restrict__ Wm,
                                                const float* __restrict__ s_read,
                                                float* __restrict__ bijD) {
    __shared__ A7Sh sh;
    #pragma unroll 1
    for (int it = 0; it < 4; ++it) {
        a7_body(blockIdx.x, sh, xT, Wm, s_read, nullptr,
                bijD + (size_t)(it & 1) * C_ * R_);
        __syncthreads();
        asm volatile("" ::: "memory");
    }
}

// ===========================================================================
// k_sqout: out[b,co] = squash(s[co][b]).  grid 160 (=co), 256 thr (=b).
// ===========================================================================
__global__ __launch_bounds__(256) void k_sqout(const float* __restrict__ s,
                                               float* __restrict__ out) {
    const int co = blockIdx.x;
    const int b  = threadIdx.x;
    out[(size_t)b * CO_ + co] = squashf(s[(size_t)co * B_ + b]);
}

// ===========================================================================
// FALLBACK tier 3 (tiny ws)
// ===========================================================================
template <bool UNIFORM>
__global__ __launch_bounds__(256) void k_s_f(const float* __restrict__ x,
                                             const float* __restrict__ Wm,
                                             const float* __restrict__ cij,
                                             float* __restrict__ s_out) {
    const int o  = threadIdx.x & 15;
    const int tb = threadIdx.x >> 4;
    const int b  = blockIdx.z * MBF_ + tb;
    const int c  = blockIdx.y;
    const int r0 = blockIdx.x * RCF_;

    const float* xp = x + ((size_t)b * R_ + r0) * I_;
    const float* wp = Wm + (((size_t)r0 * C_ + c) * O_ + o) * I_;
    const float* cp = cij + (size_t)r0 * C_ + c;

    float acc = 0.f;
    #pragma unroll 4
    for (int r = 0; r < RCF_; ++r) {
        const float4 xv0 = *(const float4*)(xp);
        const float4 xv1 = *(const float4*)(xp + 4);
        const float4 wv0 = *(const float4*)(wp);
        const float4 wv1 = *(const float4*)(wp + 4);
        const float p0 = fmaf(xv0.y, wv0.y, xv0.x * wv0.x);
        const float p1 = fmaf(xv0.w, wv0.w, xv0.z * wv0.z);
        const float p2 = fmaf(xv1.y, wv1.y, xv1.x * wv1.x);
        const float p3 = fmaf(xv1.w, wv1.w, xv1.z * wv1.z);
        const float cw = UNIFORM ? (1.0f / (float)R_) : cp[0];
        acc = fmaf(cw, (p0 + p1) + (p2 + p3), acc);
        xp += I_;
        wp += WRI_;
        cp += C_;
    }
    atomicAdd(&s_out[((size_t)b * C_ + c) * O_ + o], acc);
}

__global__ __launch_bounds__(256) void k_a_f(const float* __restrict__ x,
                                             const float* __restrict__ Wm,
                                             const float* __restrict__ s_in,
                                             float* __restrict__ amean) {
    __shared__ __align__(16) float wlds[2 * WRI_];
    __shared__ float red[4][2 * C_];

    const int tid = threadIdx.x;
    const int r0  = blockIdx.x * 2;

    const float* wsrc = Wm + (size_t)r0 * WRI_;
    #pragma unroll
    for (int k = 0; k < 2 * WRI_ / 256; ++k)
        wlds[tid + 256 * k] = wsrc[tid + 256 * k];
    __syncthreads();

    const int b    = tid;
    const int lane = tid & 63;
    const int wv   = tid >> 6;

    float xv[2][I_];
    const float4* xp4 = (const float4*)(x + ((size_t)b * R_ + r0) * I_);
    #pragma unroll
    for (int rr = 0; rr < 2; ++rr) {
        const float4 a0 = xp4[rr * 2 + 0];
        const float4 a1 = xp4[rr * 2 + 1];
        xv[rr][0] = a0.x; xv[rr][1] = a0.y; xv[rr][2] = a0.z; xv[rr][3] = a0.w;
        xv[rr][4] = a1.x; xv[rr][5] = a1.y; xv[rr][6] = a1.z; xv[rr][7] = a1.w;
    }

    #pragma unroll 1
    for (int c = 0; c < C_; ++c) {
        const float4* sp4 = (const float4*)(s_in + ((size_t)b * C_ + c) * O_);
        float v[O_];
        #pragma unroll
        for (int q = 0; q < 4; ++q) {
            const float4 sv = sp4[q];
            v[q * 4 + 0] = squashf(sv.x);
            v[q * 4 + 1] = squashf(sv.y);
            v[q * 4 + 2] = squashf(sv.z);
            v[q * 4 + 3] = squashf(sv.w);
        }
        #pragma unroll 1
        for (int rr = 0; rr < 2; ++rr) {
            const float4* wl4 = (const float4*)&wlds[(rr * C_ + c) * O_ * I_];
            float a = 0.f;
            #pragma unroll
            for (int o = 0; o < O_; ++o) {
                const float4 w0 = wl4[o * 2 + 0];
                const float4 w1 = wl4[o * 2 + 1];
                float u = xv[rr][0] * w0.x;
                u = fmaf(xv[rr][1], w0.y, u);
                u = fmaf(xv[rr][2], w0.z, u);
                u = fmaf(xv[rr][3], w0.w, u);
                u = fmaf(xv[rr][4], w1.x, u);
                u = fmaf(xv[rr][5], w1.y, u);
                u = fmaf(xv[rr][6], w1.z, u);
                u = fmaf(xv[rr][7], w1.w, u);
                a = fmaf(u, v[o], a);
            }
            #pragma unroll
            for (int off = 32; off > 0; off >>= 1)
                a += __shfl_down(a, off, 64);
            if (lane == 0) red[wv][rr * C_ + c] = a;
        }
    }

    __syncthreads();
    if (tid < 2 * C_) {
        const float t = red[0][tid] + red[1][tid] + red[2][tid] + red[3][tid];
        const int rr = tid / C_;
        const int c  = tid % C_;
        amean[(size_t)(r0 + rr) * C_ + c] = t * (1.0f / (float)B_);
    }
}

__global__ __launch_bounds__(256) void k_soft(const float* __restrict__ amean,
                                              float* __restrict__ bij,
                                              float* __restrict__ cij) {
    const int c   = blockIdx.x;
    const int tid = threadIdx.x;
    __shared__ float sred[4];

    float vals[5];
    float m = -1e30f;
    #pragma unroll
    for (int k = 0; k < 5; ++k) {
        const int r = tid + 256 * k;
        if (r < R_) {
            const size_t idx = (size_t)r * C_ + c;
            const float vv = bij[idx] + amean[idx];
            bij[idx] = vv;
            vals[k] = vv;
            m = fmaxf(m, vv);
        } else {
            vals[k] = -1e30f;
        }
    }
    #pragma unroll
    for (int off = 32; off > 0; off >>= 1)
        m = fmaxf(m, __shfl_down(m, off, 64));
    if ((tid & 63) == 0) sred[tid >> 6] = m;
    __syncthreads();
    const float bm = fmaxf(fmaxf(sred[0], sred[1]), fmaxf(sred[2], sred[3]));
    __syncthreads();

    float se = 0.f;
    #pragma unroll
    for (int k = 0; k < 5; ++k)
        se += (vals[k] > -1e29f) ? expf(vals[k] - bm) : 0.f;
    #pragma unroll
    for (int off = 32; off > 0; off >>= 1)
        se += __shfl_down(se, off, 64);
    if ((tid & 63) == 0) sred[tid >> 6] = se;
    __syncthreads();
    const float inv = 1.0f / (sred[0] + sred[1] + sred[2] + sred[3]);

    #pragma unroll
    for (int k = 0; k < 5; ++k) {
        const int r = tid + 256 * k;
        if (r < R_) cij[(size_t)r * C_ + c] = expf(vals[k] - bm) * inv;
    }
}

__global__ __launch_bounds__(256) void k_squash(float* __restrict__ s) {
    const int idx = blockIdx.x * 256 + threadIdx.x;
    if (idx < B_ * CO_) s[idx] = squashf(s[idx]);
}

} // namespace

extern "C" void kernel_launch(void* const* d_in, const int* in_sizes, int n_in,
                              void* d_out, int out_size, void* d_ws, size_t ws_size,
                              hipStream_t stream) {
    const float* x  = (const float*)d_in[0];   // [256,1152,8]
    const float* Wm = (const float*)d_in[1];   // [1152,10,16,8]
    float* out = (float*)d_out;                // [256,10,16] flat = 40960
    float* ws  = (float*)d_ws;

    const size_t need = FL_TOTAL * sizeof(float);

    if (ws_size >= need) {
        // ---------------- main path: 7 nodes + 1 diagnostic ----------------
        float* xT   = ws + XT_OFF;
        float* sA   = ws + SA_OFF;
        float* sB   = ws + SB_OFF;
        float* bijT = ws + BIJ_OFF;
        float* bijD = ws + BIJD_OFF;

        k_tr<<<1152, 256, 0, stream>>>(x, xT, sA /* = zbase, zeroes sA|sB|bij */);

        // iter 0 (uniform weights; softmax(0) == 1/R)
        k_s8<true><<<C_ * 64, 256, 0, stream>>>(xT, Wm, bijT, sA);
        k_a7<<<NA_, 320, 0, stream>>>(xT, Wm, sA, nullptr, bijT);

        // iter 1  (sB zeroed by k_tr)
        k_s8<false><<<C_ * 64, 256, 0, stream>>>(xT, Wm, bijT, sB);
        k_a7<<<NA_, 320, 0, stream>>>(xT, Wm, sB, sA /* zero for iter 2 */, bijT);

        // iter 2
        k_s8<false><<<C_ * 64, 256, 0, stream>>>(xT, Wm, bijT, sA);
        k_sqout<<<CO_, 256, 0, stream>>>(sA, out);

        // diagnostic (outputs unused; surfaces a-phase counters in top-5)
        k_a7diag<<<NA_, 320, 0, stream>>>(xT, Wm, sA, bijD);
    } else {
        // ---------------- tier 3 ----------------
        float* s_buf = ws;
        float* cij   = ws + 40960;
        float* bij   = cij + R_ * C_;
        float* amean = bij + R_ * C_;

        const dim3 gsf(KSF_, C_, B_ / MBF_);

        hipMemsetAsync(bij, 0, R_ * C_ * sizeof(float), stream);

        hipMemsetAsync(s_buf, 0, B_ * CO_ * sizeof(float), stream);
        k_s_f<true><<<gsf, 256, 0, stream>>>(x, Wm, cij, s_buf);
        k_a_f<<<R_ / 2, 256, 0, stream>>>(x, Wm, s_buf, amean);
        k_soft<<<C_, 256, 0, stream>>>(amean, bij, cij);

        hipMemsetAsync(s_buf, 0, B_ * CO_ * sizeof(float), stream);
        k_s_f<false><<<gsf, 256, 0, stream>>>(x, Wm, cij, s_buf);
        k_a_f<<<R_ / 2, 256, 0, stream>>>(x, Wm, s_buf, amean);
        k_soft<<<C_, 256, 0, stream>>>(amean, bij, cij);

        hipMemsetAsync(out, 0, B_ * CO_ * sizeof(float), stream);
        k_s_f<false><<<gsf, 256, 0, stream>>>(x, Wm, cij, out);
        k_squash<<<(B_ * CO_ + 255) / 256, 256, 0, stream>>>(out);
    }
}

// Round 8
// 195.752 us; speedup vs baseline: 1.7686x; 1.7686x over previous
//
#include <hip/hip_runtime.h>
#include <math.h>

namespace {

constexpr int B_ = 256;
constexpr int R_ = 1152;
constexpr int C_ = 10;
constexpr int O_ = 16;
constexpr int I_ = 8;
constexpr int CO_ = C_ * O_;          // 160
constexpr int WRI_ = C_ * O_ * I_;    // 1280 floats of W per route

constexpr int KS_  = 32;              // r-splits in s-phase
constexpr int RC_  = R_ / KS_;        // 36 routes per s-block

constexpr int NBA_   = 512;           // a-phase blocks (balanced: 2/CU)
constexpr int NBA2_  = 384;           // first 384 blocks: 2 routes each
                                      // last 128 blocks: 3 routes each -> 1152

// fallback tier-3 params
constexpr int KSF_ = 16;
constexpr int RCF_ = R_ / KSF_;       // 72
constexpr int MBF_ = 16;

// ws layout (float offsets) — sA|sB|bij contiguous so k_tr zeroes one range
constexpr size_t XT_OFF    = 0;                          // [R][B][I]
constexpr size_t XT_N      = (size_t)R_ * B_ * I_;       // 2,359,296
constexpr size_t SA_OFF    = XT_OFF + XT_N;              // [CO][B] raw s, iter 0/2
constexpr size_t SAB_N     = (size_t)CO_ * B_;           // 40,960
constexpr size_t SB_OFF    = SA_OFF + SAB_N;             // [CO][B] raw s, iter 1
constexpr size_t BIJ_OFF   = SB_OFF + SAB_N;             // [C][R]
constexpr size_t BIJ_N     = (size_t)C_ * R_;            // 11,520
constexpr size_t ZERO_N    = 2 * SAB_N + BIJ_N;          // 93,440 floats
constexpr size_t FL_TOTAL  = BIJ_OFF + BIJ_N;

__device__ __forceinline__ float rcp_fast(float x) {
#if defined(__has_builtin)
#if __has_builtin(__builtin_amdgcn_rcpf)
    return __builtin_amdgcn_rcpf(x);   // v_rcp_f32, ~1 ulp
#else
    return 1.0f / x;
#endif
#else
    return 1.0f / x;
#endif
}

__device__ __forceinline__ float squashf(float s) {
    // faithful to reference: s^2*s/((1+s^2)*sqrt(s^2)) == s*|s|/(1+s^2)
    return s * fabsf(s) / (1.0f + s * s);
}

// fast variant: v_rcp instead of full div sequence (~5 VALU ops vs ~10).
// r7 counters showed div was ~38% of a-kernel VALU.
__device__ __forceinline__ float squash_fast(float s) {
    return s * fabsf(s) * rcp_fast(1.0f + s * s);
}

// ===========================================================================
// k_tr: x[b,r,i] -> xT[r,b,i]; zero sA|sB|bij.  tile 8 b x 32 r.  grid 1152.
// ===========================================================================
__global__ __launch_bounds__(256) void k_tr(const float* __restrict__ x,
                                            float* __restrict__ xT,
                                            float* __restrict__ zbase) {
    __shared__ float t[8][32][8];
    const int tid = threadIdx.x;
    {
        const int gi = blockIdx.x * 256 + tid;
        if (gi < (int)(ZERO_N / 4))
            ((float4*)zbase)[gi] = make_float4(0.f, 0.f, 0.f, 0.f);
    }
    const int r0 = (blockIdx.x % 36) * 32;
    const int b0 = (blockIdx.x / 36) * 8;
    {
        const int rl = tid & 31, bl = tid >> 5;
        const float4* p = (const float4*)(x + ((size_t)(b0 + bl) * R_ + (r0 + rl)) * I_);
        const float4 a0 = p[0], a1 = p[1];
        float* d = &t[bl][rl][0];
        *(float4*)d = a0;
        *(float4*)(d + 4) = a1;
    }
    __syncthreads();
    {
        const int f = tid & 7, rw = tid >> 3;   // f = b-local
        const float* s8 = &t[f][rw][0];
        const float4 a0 = *(const float4*)s8, a1 = *(const float4*)(s8 + 4);
        float* d = xT + ((size_t)(r0 + rw) * B_ + (b0 + f)) * I_;
        *(float4*)d = a0;
        *(float4*)(d + 4) = a1;
    }
}

// ===========================================================================
// k_s8: s_dst[co][b] (+=, atomic) sum_{r in chunk} cw[r,c]*dot(W[r,c,o,:],xT[r,b,:])
// grid 640: bid = c*64 + ks*2 + bh.  c-stride 64 == 0 (mod 8): all 10
// c-copies of an x-chunk land on one XCD (L2 reuse).  NB=2 (acc[4][2]).
// ~13 us/launch per r7 ledger (2.7x VALU floor) — left unchanged this round.
// ===========================================================================
template <bool UNIFORM>
__global__ __launch_bounds__(256) void k_s8(const float* __restrict__ xT,
                                            const float* __restrict__ Wm,
                                            const float* __restrict__ bijT,
                                            float* __restrict__ s_dst) {
    __shared__ __align__(16) float wl[RC_ * 128];   // 18.4 KB
    __shared__ float cwch[RC_];
    __shared__ float sred[8];

    const int tid   = threadIdx.x;
    const int lane  = tid & 63;
    const int bid   = blockIdx.x;
    const int c     = bid >> 6;           // 0..9
    const int chunk = bid & 63;
    const int ks    = chunk >> 1;         // 0..31
    const int bh    = chunk & 1;          // 0..1
    const int r0    = ks * RC_;

    // ---- per-block softmax over routes for capsule c -> cwch[0..35] ----
    if (!UNIFORM) {
        const float* bc = bijT + (size_t)c * R_;
        float bv[5];
        float m = -1e30f;
        #pragma unroll
        for (int k = 0; k < 5; ++k) {
            const int r = tid + 256 * k;
            bv[k] = (r < R_) ? bc[r] : -1e30f;
            m = fmaxf(m, bv[k]);
        }
        #pragma unroll
        for (int off = 32; off > 0; off >>= 1)
            m = fmaxf(m, __shfl_down(m, off, 64));
        if (lane == 0) sred[tid >> 6] = m;
        __syncthreads();
        const float bm = fmaxf(fmaxf(sred[0], sred[1]), fmaxf(sred[2], sred[3]));
        float se = 0.f;
        #pragma unroll
        for (int k = 0; k < 5; ++k)
            se += (bv[k] > -1e29f) ? expf(bv[k] - bm) : 0.f;
        #pragma unroll
        for (int off = 32; off > 0; off >>= 1)
            se += __shfl_down(se, off, 64);
        if (lane == 0) sred[4 + (tid >> 6)] = se;
        __syncthreads();
        const float inv = 1.0f / (sred[4] + sred[5] + sred[6] + sred[7]);
        if (tid < RC_) cwch[tid] = expf(bc[r0 + tid] - bm) * inv;
        __syncthreads();
    }

    // ---- stage cw-scaled W chunk: 36 r x 32 f4 = 1152 f4 ----
    {
        const float4* src = (const float4*)(Wm + ((size_t)r0 * C_ + c) * 128);
        float4* dst = (float4*)wl;
        #pragma unroll
        for (int k = 0; k < (RC_ * 32 + 255) / 256; ++k) {
            const int idx = tid + 256 * k;
            if (idx < RC_ * 32) {
                const int r = idx >> 5, q = idx & 31;
                float4 wv = src[(size_t)r * (C_ * 32) + q];
                const float cw = UNIFORM ? (1.0f / (float)R_) : cwch[r];
                wv.x *= cw; wv.y *= cw; wv.z *= cw; wv.w *= cw;
                dst[idx] = wv;
            }
        }
    }
    __syncthreads();

    const int o0 = (tid >> 6) * 4;        // wave-uniform -> LDS broadcast reads
    const float* xbase = xT + ((size_t)r0 * B_ + bh * 128 + lane) * I_;

    float acc[4][2];
    #pragma unroll
    for (int oo = 0; oo < 4; ++oo) { acc[oo][0] = 0.f; acc[oo][1] = 0.f; }

    #pragma unroll 2
    for (int r = 0; r < RC_; ++r) {
        const float* xr = xbase + (size_t)r * B_ * I_;
        const float4 a00 = ((const float4*)xr)[0];
        const float4 a01 = ((const float4*)xr)[1];
        const float4 a10 = ((const float4*)(xr + 64 * I_))[0];
        const float4 a11 = ((const float4*)(xr + 64 * I_))[1];
        const float4* wp = (const float4*)&wl[r * 128 + o0 * 8];
        #pragma unroll
        for (int oo = 0; oo < 4; ++oo) {
            const float4 w0 = wp[oo * 2 + 0];
            const float4 w1 = wp[oo * 2 + 1];
            float a = acc[oo][0];
            a = fmaf(a00.x, w0.x, a);
            a = fmaf(a00.y, w0.y, a);
            a = fmaf(a00.z, w0.z, a);
            a = fmaf(a00.w, w0.w, a);
            a = fmaf(a01.x, w1.x, a);
            a = fmaf(a01.y, w1.y, a);
            a = fmaf(a01.z, w1.z, a);
            a = fmaf(a01.w, w1.w, a);
            acc[oo][0] = a;
            float b = acc[oo][1];
            b = fmaf(a10.x, w0.x, b);
            b = fmaf(a10.y, w0.y, b);
            b = fmaf(a10.z, w0.z, b);
            b = fmaf(a10.w, w0.w, b);
            b = fmaf(a11.x, w1.x, b);
            b = fmaf(a11.y, w1.y, b);
            b = fmaf(a11.z, w1.z, b);
            b = fmaf(a11.w, w1.w, b);
            acc[oo][1] = b;
        }
    }

    float* sp = s_dst + (size_t)(c * O_ + o0) * B_ + bh * 128 + lane;
    #pragma unroll
    for (int oo = 0; oo < 4; ++oo) {
        atomicAdd(sp + (size_t)oo * B_, acc[oo][0]);
        atomicAdd(sp + (size_t)oo * B_ + 64, acc[oo][1]);
    }
}

// ===========================================================================
// a8_body<NR>: bij_dst[c, r0+rr] += (1/B) sum_{o,i} W[r,c,o,i] *
//              (sum_b squash(s_read[co][b]) * xT[r,b,i])
// 320 thr = 40 co-QUADS x 8 b-groups of 32.  Changes vs r7 a7 (41 us):
//  - 4 co per thread: x LDS reads HALVED (128/thr), 16 fma per read.
//  - x LDS XOR-swizzled (e' = e ^ ((e>>6)&7), thread-constant XOR by bg):
//    the 2 wave-addresses now hit different bank groups (was same-bank,
//    +4 cyc on every b128 read = 5.97M conflict cycles in r7).
//  - squash via v_rcp (was full div sequence, ~38% of VALU).
//  - balanced grid: 384 blocks x 2 routes + 128 x 3 = 512 = 2/CU exactly.
// ===========================================================================
struct A8Sh {
    float4 xsw[3 * 512];     // swizzled x, up to 3 routes (24 KB)
    float  part[3][320];     // 3.75 KB
};

template <int NR>
__device__ __forceinline__ void a8_body(int r0, A8Sh& sh,
                                        const float* __restrict__ xT,
                                        const float* __restrict__ Wm,
                                        const float* __restrict__ s_read,
                                        float* __restrict__ bij_dst) {
    const int tid = threadIdx.x;

    // ---- stage x chunk, swizzled: e' = e ^ ((e>>6)&7) (involution) ----
    {
        const float4* src = (const float4*)(xT + (size_t)r0 * B_ * I_);
        for (int k = tid; k < NR * 512; k += 320)
            sh.xsw[k ^ ((k >> 6) & 7)] = src[k];
    }
    __syncthreads();

    const int cq = tid % 40;          // co quad: co = 4cq..4cq+3 (one capsule)
    const int bg = tid / 40;          // 0..7, 32 b each
    const int b0 = bg * 32;

    float acc[NR][4][8];
    #pragma unroll
    for (int rr = 0; rr < NR; ++rr)
        #pragma unroll
        for (int j = 0; j < 4; ++j)
            #pragma unroll
            for (int i = 0; i < 8; ++i) acc[rr][j][i] = 0.f;

    const float* vbase = s_read + (size_t)(4 * cq) * B_ + b0;   // [co][b]

    #pragma unroll 2
    for (int bb = 0; bb < 32; bb += 4) {
        float va[4][4];               // [co j][b j2], squashed
        #pragma unroll
        for (int j = 0; j < 4; ++j) {
            const float4 t = *(const float4*)(vbase + (size_t)j * B_ + bb);
            va[j][0] = squash_fast(t.x);
            va[j][1] = squash_fast(t.y);
            va[j][2] = squash_fast(t.z);
            va[j][3] = squash_fast(t.w);
        }
        #pragma unroll
        for (int j2 = 0; j2 < 4; ++j2) {
            const int eb = (b0 + bb + j2) * 2;
            #pragma unroll
            for (int rr = 0; rr < NR; ++rr) {
                const float4 x0 = sh.xsw[(rr * 512 + eb) ^ bg];
                const float4 x1 = sh.xsw[(rr * 512 + eb + 1) ^ bg];
                #pragma unroll
                for (int j = 0; j < 4; ++j) {
                    const float w = va[j][j2];
                    acc[rr][j][0] = fmaf(w, x0.x, acc[rr][j][0]);
                    acc[rr][j][1] = fmaf(w, x0.y, acc[rr][j][1]);
                    acc[rr][j][2] = fmaf(w, x0.z, acc[rr][j][2]);
                    acc[rr][j][3] = fmaf(w, x0.w, acc[rr][j][3]);
                    acc[rr][j][4] = fmaf(w, x1.x, acc[rr][j][4]);
                    acc[rr][j][5] = fmaf(w, x1.y, acc[rr][j][5]);
                    acc[rr][j][6] = fmaf(w, x1.z, acc[rr][j][6]);
                    acc[rr][j][7] = fmaf(w, x1.w, acc[rr][j][7]);
                }
            }
        }
    }

    // ---- W-dot epilogue: thread's 4 co are within one capsule ----
    #pragma unroll
    for (int rr = 0; rr < NR; ++rr) {
        const float* wp = Wm + (((size_t)(r0 + rr)) * CO_ + 4 * cq) * I_;
        float psum = 0.f;
        #pragma unroll
        for (int j = 0; j < 4; ++j) {
            const float4 w0 = *(const float4*)(wp + j * 8);
            const float4 w1 = *(const float4*)(wp + j * 8 + 4);
            float p = acc[rr][j][0] * w0.x;
            p = fmaf(acc[rr][j][1], w0.y, p);
            p = fmaf(acc[rr][j][2], w0.z, p);
            p = fmaf(acc[rr][j][3], w0.w, p);
            p = fmaf(acc[rr][j][4], w1.x, p);
            p = fmaf(acc[rr][j][5], w1.y, p);
            p = fmaf(acc[rr][j][6], w1.z, p);
            p = fmaf(acc[rr][j][7], w1.w, p);
            psum += p;
        }
        sh.part[rr][tid] = psum;
    }
    __syncthreads();

    // reduce: per (rr, capsule): 8 bg x 4 cq-of-capsule = 32 partials
    if (tid < NR * C_) {
        const int r = tid / C_, c2 = tid % C_;
        float s = 0.f;
        #pragma unroll
        for (int g2 = 0; g2 < 8; ++g2)
            #pragma unroll
            for (int q = 0; q < 4; ++q)
                s += sh.part[r][g2 * 40 + c2 * 4 + q];
        bij_dst[(size_t)c2 * R_ + (r0 + r)] += s * (1.0f / (float)B_);
    }
}

__global__ __launch_bounds__(320) void k_a8(const float* __restrict__ xT,
                                            const float* __restrict__ Wm,
                                            const float* __restrict__ s_read,
                                            float* __restrict__ s_zero,
                                            float* __restrict__ bijT) {
    __shared__ A8Sh sh;
    const int bid = blockIdx.x;
    if (s_zero != nullptr && bid < 40 && threadIdx.x < 256) {
        ((float4*)s_zero)[bid * 256 + threadIdx.x] =
            make_float4(0.f, 0.f, 0.f, 0.f);
    }
    if (bid < NBA2_) {
        a8_body<2>(bid * 2, sh, xT, Wm, s_read, bijT);
    } else {
        a8_body<3>(NBA2_ * 2 + (bid - NBA2_) * 3, sh, xT, Wm, s_read, bijT);
    }
}

// ===========================================================================
// k_sqout: out[b,co] = squash(s[co][b]).  grid 160 (=co), 256 thr (=b).
// ===========================================================================
__global__ __launch_bounds__(256) void k_sqout(const float* __restrict__ s,
                                               float* __restrict__ out) {
    const int co = blockIdx.x;
    const int b  = threadIdx.x;
    out[(size_t)b * CO_ + co] = squash_fast(s[(size_t)co * B_ + b]);
}

// ===========================================================================
// FALLBACK tier 3 (tiny ws)
// ===========================================================================
template <bool UNIFORM>
__global__ __launch_bounds__(256) void k_s_f(const float* __restrict__ x,
                                             const float* __restrict__ Wm,
                                             const float* __restrict__ cij,
                                             float* __restrict__ s_out) {
    const int o  = threadIdx.x & 15;
    const int tb = threadIdx.x >> 4;
    const int b  = blockIdx.z * MBF_ + tb;
    const int c  = blockIdx.y;
    const int r0 = blockIdx.x * RCF_;

    const float* xp = x + ((size_t)b * R_ + r0) * I_;
    const float* wp = Wm + (((size_t)r0 * C_ + c) * O_ + o) * I_;
    const float* cp = cij + (size_t)r0 * C_ + c;

    float acc = 0.f;
    #pragma unroll 4
    for (int r = 0; r < RCF_; ++r) {
        const float4 xv0 = *(const float4*)(xp);
        const float4 xv1 = *(const float4*)(xp + 4);
        const float4 wv0 = *(const float4*)(wp);
        const float4 wv1 = *(const float4*)(wp + 4);
        const float p0 = fmaf(xv0.y, wv0.y, xv0.x * wv0.x);
        const float p1 = fmaf(xv0.w, wv0.w, xv0.z * wv0.z);
        const float p2 = fmaf(xv1.y, wv1.y, xv1.x * wv1.x);
        const float p3 = fmaf(xv1.w, wv1.w, xv1.z * wv1.z);
        const float cw = UNIFORM ? (1.0f / (float)R_) : cp[0];
        acc = fmaf(cw, (p0 + p1) + (p2 + p3), acc);
        xp += I_;
        wp += WRI_;
        cp += C_;
    }
    atomicAdd(&s_out[((size_t)b * C_ + c) * O_ + o], acc);
}

__global__ __launch_bounds__(256) void k_a_f(const float* __restrict__ x,
                                             const float* __restrict__ Wm,
                                             const float* __restrict__ s_in,
                                             float* __restrict__ amean) {
    __shared__ __align__(16) float wlds[2 * WRI_];
    __shared__ float red[4][2 * C_];

    const int tid = threadIdx.x;
    const int r0  = blockIdx.x * 2;

    const float* wsrc = Wm + (size_t)r0 * WRI_;
    #pragma unroll
    for (int k = 0; k < 2 * WRI_ / 256; ++k)
        wlds[tid + 256 * k] = wsrc[tid + 256 * k];
    __syncthreads();

    const int b    = tid;
    const int lane = tid & 63;
    const int wv   = tid >> 6;

    float xv[2][I_];
    const float4* xp4 = (const float4*)(x + ((size_t)b * R_ + r0) * I_);
    #pragma unroll
    for (int rr = 0; rr < 2; ++rr) {
        const float4 a0 = xp4[rr * 2 + 0];
        const float4 a1 = xp4[rr * 2 + 1];
        xv[rr][0] = a0.x; xv[rr][1] = a0.y; xv[rr][2] = a0.z; xv[rr][3] = a0.w;
        xv[rr][4] = a1.x; xv[rr][5] = a1.y; xv[rr][6] = a1.z; xv[rr][7] = a1.w;
    }

    #pragma unroll 1
    for (int c = 0; c < C_; ++c) {
        const float4* sp4 = (const float4*)(s_in + ((size_t)b * C_ + c) * O_);
        float v[O_];
        #pragma unroll
        for (int q = 0; q < 4; ++q) {
            const float4 sv = sp4[q];
            v[q * 4 + 0] = squashf(sv.x);
            v[q * 4 + 1] = squashf(sv.y);
            v[q * 4 + 2] = squashf(sv.z);
            v[q * 4 + 3] = squashf(sv.w);
        }
        #pragma unroll 1
        for (int rr = 0; rr < 2; ++rr) {
            const float4* wl4 = (const float4*)&wlds[(rr * C_ + c) * O_ * I_];
            float a = 0.f;
            #pragma unroll
            for (int o = 0; o < O_; ++o) {
                const float4 w0 = wl4[o * 2 + 0];
                const float4 w1 = wl4[o * 2 + 1];
                float u = xv[rr][0] * w0.x;
                u = fmaf(xv[rr][1], w0.y, u);
                u = fmaf(xv[rr][2], w0.z, u);
                u = fmaf(xv[rr][3], w0.w, u);
                u = fmaf(xv[rr][4], w1.x, u);
                u = fmaf(xv[rr][5], w1.y, u);
                u = fmaf(xv[rr][6], w1.z, u);
                u = fmaf(xv[rr][7], w1.w, u);
                a = fmaf(u, v[o], a);
            }
            #pragma unroll
            for (int off = 32; off > 0; off >>= 1)
                a += __shfl_down(a, off, 64);
            if (lane == 0) red[wv][rr * C_ + c] = a;
        }
    }

    __syncthreads();
    if (tid < 2 * C_) {
        const float t = red[0][tid] + red[1][tid] + red[2][tid] + red[3][tid];
        const int rr = tid / C_;
        const int c  = tid % C_;
        amean[(size_t)(r0 + rr) * C_ + c] = t * (1.0f / (float)B_);
    }
}

__global__ __launch_bounds__(256) void k_soft(const float* __restrict__ amean,
                                              float* __restrict__ bij,
                                              float* __restrict__ cij) {
    const int c   = blockIdx.x;
    const int tid = threadIdx.x;
    __shared__ float sred[4];

    float vals[5];
    float m = -1e30f;
    #pragma unroll
    for (int k = 0; k < 5; ++k) {
        const int r = tid + 256 * k;
        if (r < R_) {
            const size_t idx = (size_t)r * C_ + c;
            const float vv = bij[idx] + amean[idx];
            bij[idx] = vv;
            vals[k] = vv;
            m = fmaxf(m, vv);
        } else {
            vals[k] = -1e30f;
        }
    }
    #pragma unroll
    for (int off = 32; off > 0; off >>= 1)
        m = fmaxf(m, __shfl_down(m, off, 64));
    if ((tid & 63) == 0) sred[tid >> 6] = m;
    __syncthreads();
    const float bm = fmaxf(fmaxf(sred[0], sred[1]), fmaxf(sred[2], sred[3]));
    __syncthreads();

    float se = 0.f;
    #pragma unroll
    for (int k = 0; k < 5; ++k)
        se += (vals[k] > -1e29f) ? expf(vals[k] - bm) : 0.f;
    #pragma unroll
    for (int off = 32; off > 0; off >>= 1)
        se += __shfl_down(se, off, 64);
    if ((tid & 63) == 0) sred[tid >> 6] = se;
    __syncthreads();
    const float inv = 1.0f / (sred[0] + sred[1] + sred[2] + sred[3]);

    #pragma unroll
    for (int k = 0; k < 5; ++k) {
        const int r = tid + 256 * k;
        if (r < R_) cij[(size_t)r * C_ + c] = expf(vals[k] - bm) * inv;
    }
}

__global__ __launch_bounds__(256) void k_squash(float* __restrict__ s) {
    const int idx = blockIdx.x * 256 + threadIdx.x;
    if (idx < B_ * CO_) s[idx] = squashf(s[idx]);
}

} // namespace

extern "C" void kernel_launch(void* const* d_in, const int* in_sizes, int n_in,
                              void* d_out, int out_size, void* d_ws, size_t ws_size,
                              hipStream_t stream) {
    const float* x  = (const float*)d_in[0];   // [256,1152,8]
    const float* Wm = (const float*)d_in[1];   // [1152,10,16,8]
    float* out = (float*)d_out;                // [256,10,16] flat = 40960
    float* ws  = (float*)d_ws;

    const size_t need = FL_TOTAL * sizeof(float);

    if (ws_size >= need) {
        // ---------------- main path: 7 nodes ----------------
        float* xT   = ws + XT_OFF;
        float* sA   = ws + SA_OFF;
        float* sB   = ws + SB_OFF;
        float* bijT = ws + BIJ_OFF;

        k_tr<<<1152, 256, 0, stream>>>(x, xT, sA /* = zbase, zeroes sA|sB|bij */);

        // iter 0 (uniform weights; softmax(0) == 1/R)
        k_s8<true><<<C_ * 64, 256, 0, stream>>>(xT, Wm, bijT, sA);
        k_a8<<<NBA_, 320, 0, stream>>>(xT, Wm, sA, nullptr, bijT);

        // iter 1  (sB zeroed by k_tr)
        k_s8<false><<<C_ * 64, 256, 0, stream>>>(xT, Wm, bijT, sB);
        k_a8<<<NBA_, 320, 0, stream>>>(xT, Wm, sB, sA /* zero for iter 2 */, bijT);

        // iter 2
        k_s8<false><<<C_ * 64, 256, 0, stream>>>(xT, Wm, bijT, sA);
        k_sqout<<<CO_, 256, 0, stream>>>(sA, out);
    } else {
        // ---------------- tier 3 ----------------
        float* s_buf = ws;
        float* cij   = ws + 40960;
        float* bij   = cij + R_ * C_;
        float* amean = bij + R_ * C_;

        const dim3 gsf(KSF_, C_, B_ / MBF_);

        hipMemsetAsync(bij, 0, R_ * C_ * sizeof(float), stream);

        hipMemsetAsync(s_buf, 0, B_ * CO_ * sizeof(float), stream);
        k_s_f<true><<<gsf, 256, 0, stream>>>(x, Wm, cij, s_buf);
        k_a_f<<<R_ / 2, 256, 0, stream>>>(x, Wm, s_buf, amean);
        k_soft<<<C_, 256, 0, stream>>>(amean, bij, cij);

        hipMemsetAsync(s_buf, 0, B_ * CO_ * sizeof(float), stream);
        k_s_f<false><<<gsf, 256, 0, stream>>>(x, Wm, cij, s_buf);
        k_a_f<<<R_ / 2, 256, 0, stream>>>(x, Wm, s_buf, amean);
        k_soft<<<C_, 256, 0, stream>>>(amean, bij, cij);

        hipMemsetAsync(out, 0, B_ * CO_ * sizeof(float), stream);
        k_s_f<false><<<gsf, 256, 0, stream>>>(x, Wm, cij, out);
        k_squash<<<(B_ * CO_ + 255) / 256, 256, 0, stream>>>(out);
    }
}